// Round 1
// baseline (51.595 us; speedup 1.0000x reference)
//
#include <hip/hip_runtime.h>
#include <math.h>

// Problem constants (match reference setup_inputs)
#define KF   11
#define PAD  5          // KF/2
#define NB   4
#define CH   3
#define HH   256
#define WW   256
#define HWSZ (HH * WW)
#define EPS2 (1e-3f * 1e-3f)

// Kernel 1: one thread per (n, h, w). Each thread computes the reconstruction
// for all 3 channels (filters shared across channels -> filters read once),
// the Charbonnier terms, and participates in a block tree-reduction.
// Block = 256 threads = one image row (w = threadIdx.x). Grid = N*H = 1024.
__global__ __launch_bounds__(256) void recon_charbonnier_kernel(
    const float* __restrict__ image1,
    const float* __restrict__ image2,
    const float* __restrict__ filters,
    float* __restrict__ block_sums)
{
    const int w  = threadIdx.x;        // 0..255
    const int nh = blockIdx.x;         // n*H + h
    const int n  = nh >> 8;
    const int h  = nh & 255;

    // filter pointer for this pixel: filters[n, t, h, w], tap stride = HWSZ
    const float* __restrict__ fptr = filters + (size_t)n * (KF * KF) * HWSZ
                                             + (size_t)h * WW + w;
    const float* __restrict__ img1n = image1 + (size_t)n * CH * HWSZ;

    float rec0 = 0.f, rec1 = 0.f, rec2 = 0.f;

    int t = 0;
    for (int dh = 0; dh < KF; ++dh) {
        const int hh = h + dh - PAD;
        const bool hok = (unsigned)hh < (unsigned)HH;
        const float* __restrict__ r0 = img1n + 0 * HWSZ + (size_t)hh * WW;
        const float* __restrict__ r1 = img1n + 1 * HWSZ + (size_t)hh * WW;
        const float* __restrict__ r2 = img1n + 2 * HWSZ + (size_t)hh * WW;
        #pragma unroll
        for (int dw = 0; dw < KF; ++dw, ++t) {
            const float f = fptr[(size_t)t * HWSZ];   // coalesced across lanes
            const int ww = w + dw - PAD;
            if (hok && (unsigned)ww < (unsigned)WW) {
                rec0 = fmaf(f, r0[ww], rec0);
                rec1 = fmaf(f, r1[ww], rec1);
                rec2 = fmaf(f, r2[ww], rec2);
            }
        }
    }

    const float* __restrict__ img2p = image2 + (size_t)n * CH * HWSZ
                                            + (size_t)h * WW + w;
    const float d0 = rec0 - img2p[0 * HWSZ];
    const float d1 = rec1 - img2p[1 * HWSZ];
    const float d2 = rec2 - img2p[2 * HWSZ];

    float s = sqrtf(d0 * d0 + EPS2) + sqrtf(d1 * d1 + EPS2)
            + sqrtf(d2 * d2 + EPS2);

    // ---- block reduction (256 threads = 4 waves of 64) ----
    #pragma unroll
    for (int off = 32; off > 0; off >>= 1)
        s += __shfl_down(s, off, 64);

    __shared__ float wsum[4];
    if ((threadIdx.x & 63) == 0) wsum[threadIdx.x >> 6] = s;
    __syncthreads();
    if (threadIdx.x == 0)
        block_sums[blockIdx.x] = (wsum[0] + wsum[1]) + (wsum[2] + wsum[3]);
}

// Kernel 2: reduce the 1024 per-block sums into the scalar mean.
__global__ __launch_bounds__(256) void final_reduce_kernel(
    const float* __restrict__ block_sums,
    float* __restrict__ out)
{
    float s = 0.f;
    #pragma unroll
    for (int i = 0; i < 4; ++i)
        s += block_sums[threadIdx.x + i * 256];

    #pragma unroll
    for (int off = 32; off > 0; off >>= 1)
        s += __shfl_down(s, off, 64);

    __shared__ float wsum[4];
    if ((threadIdx.x & 63) == 0) wsum[threadIdx.x >> 6] = s;
    __syncthreads();
    if (threadIdx.x == 0) {
        const float inv_count = 1.0f / (float)(NB * CH * HH * WW);
        out[0] = ((wsum[0] + wsum[1]) + (wsum[2] + wsum[3])) * inv_count;
    }
}

extern "C" void kernel_launch(void* const* d_in, const int* in_sizes, int n_in,
                              void* d_out, int out_size, void* d_ws, size_t ws_size,
                              hipStream_t stream) {
    const float* image1  = (const float*)d_in[0];
    const float* image2  = (const float*)d_in[1];
    const float* filters = (const float*)d_in[2];
    float* out = (float*)d_out;
    float* block_sums = (float*)d_ws;   // 1024 floats

    const int grid = NB * HH;           // 1024 blocks, one per (n, h) row

    recon_charbonnier_kernel<<<grid, 256, 0, stream>>>(image1, image2, filters,
                                                       block_sums);
    final_reduce_kernel<<<1, 256, 0, stream>>>(block_sums, out);
}

// Round 2
// 31.991 us; speedup vs baseline: 1.6128x; 1.6128x over previous
//
#include <hip/hip_runtime.h>
#include <math.h>

// Problem constants (match reference setup_inputs)
#define KF   11
#define PAD  5          // KF/2
#define NB   4
#define CH   3
#define HH   256
#define WW   256
#define HWSZ (HH * WW)
#define EPS2 (1e-3f * 1e-3f)

#define LW    272            // padded LDS row width (266 used: 256 + 2*PAD)
#define LROWS (CH * KF)      // 33 rows staged
#define LTOT  (LROWS * LW)   // 8976 floats

// One block (512 threads) per (n, h) output row.
//   - Stage image1 rows h-5..h+5 x 3 channels into LDS with zero-padded halo
//     (removes 363 vmem loads/thread and all inner-loop predication).
//   - Threads tid=0..255 (half 0) handle tap rows dh=0..5 for pixel w=tid;
//     threads 256..511 (half 1) handle dh=6..10 for pixel w=tid-256.
//     -> 8192 waves total = 100% occupancy ceiling.
//   - Partial reconstructions combined via LDS, then Charbonnier + reduce.
__global__ __launch_bounds__(512, 8) void recon_charbonnier_kernel(
    const float* __restrict__ image1,
    const float* __restrict__ image2,
    const float* __restrict__ filters,
    float* __restrict__ block_sums)
{
    __shared__ float limg[LROWS][LW];   // [ch*KF + dh][col] 35904 B
    __shared__ float part[CH][WW];      // 3072 B
    __shared__ float wsum[8];

    const int tid  = threadIdx.x;
    const int pix  = tid & 255;
    const int half = tid >> 8;          // 0 or 1
    const int nh   = blockIdx.x;
    const int n    = nh >> 8;
    const int h    = nh & 255;

    const float* __restrict__ img1n = image1 + (size_t)n * CH * HWSZ;

    // ---- stage image1 neighborhood into LDS (zero-padded) ----
    for (int idx = tid; idx < LTOT; idx += 512) {
        const int ch  = idx / (KF * LW);
        const int rem = idx - ch * (KF * LW);
        const int r   = rem / LW;            // dh 0..10
        const int c   = rem - r * LW;        // 0..271
        const int grow = h + r - PAD;
        const int gcol = c - PAD;
        float v = 0.f;
        if ((unsigned)grow < (unsigned)HH && (unsigned)gcol < (unsigned)WW)
            v = img1n[(size_t)ch * HWSZ + (size_t)grow * WW + gcol];
        ((float*)limg)[idx] = v;
    }
    __syncthreads();

    // ---- tap loop: only filter loads touch vmem ----
    const float* __restrict__ fptr = filters + (size_t)n * (KF * KF) * HWSZ
                                             + (size_t)h * WW + pix;
    float rec0 = 0.f, rec1 = 0.f, rec2 = 0.f;

    const int dhBeg = half * 6;               // 0 or 6
    const int dhEnd = half ? KF : 6;          // 6 or 11
    for (int dh = dhBeg; dh < dhEnd; ++dh) {
        const float* __restrict__ frow = fptr + (size_t)(dh * KF) * HWSZ;
        float fv[KF];
        #pragma unroll
        for (int dw = 0; dw < KF; ++dw)
            fv[dw] = frow[(size_t)dw * HWSZ];     // 11 independent coalesced loads
        #pragma unroll
        for (int dw = 0; dw < KF; ++dw) {
            rec0 = fmaf(fv[dw], limg[0 * KF + dh][pix + dw], rec0);
            rec1 = fmaf(fv[dw], limg[1 * KF + dh][pix + dw], rec1);
            rec2 = fmaf(fv[dw], limg[2 * KF + dh][pix + dw], rec2);
        }
    }

    // ---- combine halves, Charbonnier ----
    if (half) {
        part[0][pix] = rec0;
        part[1][pix] = rec1;
        part[2][pix] = rec2;
    }
    __syncthreads();

    float s = 0.f;
    if (!half) {
        const float* __restrict__ img2p = image2 + (size_t)n * CH * HWSZ
                                                 + (size_t)h * WW + pix;
        const float d0 = rec0 + part[0][pix] - img2p[0 * HWSZ];
        const float d1 = rec1 + part[1][pix] - img2p[1 * HWSZ];
        const float d2 = rec2 + part[2][pix] - img2p[2 * HWSZ];
        s = sqrtf(d0 * d0 + EPS2) + sqrtf(d1 * d1 + EPS2)
          + sqrtf(d2 * d2 + EPS2);
    }

    // ---- block reduction (512 threads = 8 waves) ----
    #pragma unroll
    for (int off = 32; off > 0; off >>= 1)
        s += __shfl_down(s, off, 64);
    if ((tid & 63) == 0) wsum[tid >> 6] = s;
    __syncthreads();
    if (tid == 0) {
        float t = 0.f;
        #pragma unroll
        for (int i = 0; i < 8; ++i) t += wsum[i];
        block_sums[blockIdx.x] = t;
    }
}

// Kernel 2: reduce the 1024 per-block sums into the scalar mean.
__global__ __launch_bounds__(256) void final_reduce_kernel(
    const float* __restrict__ block_sums,
    float* __restrict__ out)
{
    float s = 0.f;
    #pragma unroll
    for (int i = 0; i < 4; ++i)
        s += block_sums[threadIdx.x + i * 256];

    #pragma unroll
    for (int off = 32; off > 0; off >>= 1)
        s += __shfl_down(s, off, 64);

    __shared__ float wsum[4];
    if ((threadIdx.x & 63) == 0) wsum[threadIdx.x >> 6] = s;
    __syncthreads();
    if (threadIdx.x == 0) {
        const float inv_count = 1.0f / (float)(NB * CH * HH * WW);
        out[0] = ((wsum[0] + wsum[1]) + (wsum[2] + wsum[3])) * inv_count;
    }
}

extern "C" void kernel_launch(void* const* d_in, const int* in_sizes, int n_in,
                              void* d_out, int out_size, void* d_ws, size_t ws_size,
                              hipStream_t stream) {
    const float* image1  = (const float*)d_in[0];
    const float* image2  = (const float*)d_in[1];
    const float* filters = (const float*)d_in[2];
    float* out = (float*)d_out;
    float* block_sums = (float*)d_ws;   // 1024 floats

    const int grid = NB * HH;           // 1024 blocks, one per (n, h) row

    recon_charbonnier_kernel<<<grid, 512, 0, stream>>>(image1, image2, filters,
                                                       block_sums);
    final_reduce_kernel<<<1, 256, 0, stream>>>(block_sums, out);
}

// Round 3
// 30.863 us; speedup vs baseline: 1.6717x; 1.0365x over previous
//
#include <hip/hip_runtime.h>
#include <math.h>

// Problem constants (match reference setup_inputs)
#define KF   11
#define PAD  5          // KF/2
#define NB   4
#define CH   3
#define HH   256
#define WW   256
#define HWSZ (HH * WW)
#define EPS2 (1e-3f * 1e-3f)

#define RPB   4                    // output rows per block
#define SROWS (RPB + KF - 1)       // 14 staged rows per channel
#define LW    272                  // LDS row width (floats); col = gcol + LPAD
#define LPAD  8                    // left pad (keeps float4 staging writes 16B-aligned)
#define LW4   (LW / 4)             // 68 float4 per LDS row
#define STOT  (CH * SROWS * LW4)   // 2856 float4 staging elements

// One block (256 threads) per (n, 4-row band). Thread layout:
//   p = tid & 63  -> pixel quad  w = 4p .. 4p+3
//   r = tid >> 6  -> output row  h = h0 + r   (each wave owns one row)
// All global loads are float4 (1 KB/wave/instr); LDS window reads are
// compiler-merged wide ds_reads (per-lane byte base 16p+12).
__global__ __launch_bounds__(256) void recon_charbonnier_kernel(
    const float* __restrict__ image1,
    const float* __restrict__ image2,
    const float* __restrict__ filters,
    float* __restrict__ block_sums)
{
    __shared__ float limg[CH][SROWS][LW];   // 45,696 B
    __shared__ float wsum[4];

    const int tid = threadIdx.x;
    const int p   = tid & 63;
    const int r   = tid >> 6;
    const int b   = blockIdx.x;
    const int n   = b >> 6;            // 4 batches
    const int h0  = (b & 63) << 2;     // 64 bands of 4 rows

    const float* __restrict__ img1n = image1 + (size_t)n * CH * HWSZ;

    // ---- stage image1 band (rows h0-5 .. h0+8, 3 ch) into LDS, zero halo ----
    for (int idx = tid; idx < STOT; idx += 256) {
        const int row = idx / LW4;            // 0..41  (ch*SROWS + rr)
        const int c4  = idx - row * LW4;      // 0..67
        const int ch  = row / SROWS;
        const int rr  = row - ch * SROWS;
        const int grow = h0 + rr - PAD;
        const int gcol = (c4 << 2) - LPAD;
        float4 v = make_float4(0.f, 0.f, 0.f, 0.f);
        if ((unsigned)grow < (unsigned)HH && (unsigned)gcol <= (unsigned)(WW - 4))
            v = *(const float4*)(img1n + (size_t)ch * HWSZ
                                       + (size_t)grow * WW + gcol);
        *(float4*)&limg[ch][rr][c4 << 2] = v;   // byte offset 16*c4: aligned
    }
    __syncthreads();

    // ---- tap loop: float4 filter loads + wide LDS window reads ----
    const int w0 = p << 2;
    const float* __restrict__ fp = filters + (size_t)n * (KF * KF) * HWSZ
                                           + (size_t)(h0 + r) * WW + w0;

    float acc[CH][4] = {};

    for (int dh = 0; dh < KF; ++dh) {
        float4 fv[KF];
        #pragma unroll
        for (int dw = 0; dw < KF; ++dw)
            fv[dw] = *(const float4*)(fp + (size_t)(dh * KF + dw) * HWSZ);

        #pragma unroll
        for (int ch = 0; ch < CH; ++ch) {
            // win[j] = image1[ch][h0+r+dh-5][w0 + j - 5]  (zero-padded)
            const float* __restrict__ lrow = &limg[ch][r + dh][w0 + 3];
            float win[16];
            #pragma unroll
            for (int j = 0; j < 16; ++j) win[j] = lrow[j];

            #pragma unroll
            for (int dw = 0; dw < KF; ++dw) {
                acc[ch][0] = fmaf(fv[dw].x, win[dw + 0], acc[ch][0]);
                acc[ch][1] = fmaf(fv[dw].y, win[dw + 1], acc[ch][1]);
                acc[ch][2] = fmaf(fv[dw].z, win[dw + 2], acc[ch][2]);
                acc[ch][3] = fmaf(fv[dw].w, win[dw + 3], acc[ch][3]);
            }
        }
    }

    // ---- Charbonnier over 3 ch x 4 px ----
    const float* __restrict__ img2p = image2 + (size_t)n * CH * HWSZ
                                             + (size_t)(h0 + r) * WW + w0;
    float s = 0.f;
    #pragma unroll
    for (int ch = 0; ch < CH; ++ch) {
        const float4 t2 = *(const float4*)(img2p + (size_t)ch * HWSZ);
        const float d0 = acc[ch][0] - t2.x;
        const float d1 = acc[ch][1] - t2.y;
        const float d2 = acc[ch][2] - t2.z;
        const float d3 = acc[ch][3] - t2.w;
        s += sqrtf(d0 * d0 + EPS2) + sqrtf(d1 * d1 + EPS2)
           + sqrtf(d2 * d2 + EPS2) + sqrtf(d3 * d3 + EPS2);
    }

    // ---- block reduction (4 waves of 64) ----
    #pragma unroll
    for (int off = 32; off > 0; off >>= 1)
        s += __shfl_down(s, off, 64);
    if ((tid & 63) == 0) wsum[tid >> 6] = s;
    __syncthreads();
    if (tid == 0)
        block_sums[blockIdx.x] = (wsum[0] + wsum[1]) + (wsum[2] + wsum[3]);
}

// Kernel 2: reduce the 256 per-block sums into the scalar mean.
__global__ __launch_bounds__(256) void final_reduce_kernel(
    const float* __restrict__ block_sums,
    float* __restrict__ out)
{
    float s = block_sums[threadIdx.x];

    #pragma unroll
    for (int off = 32; off > 0; off >>= 1)
        s += __shfl_down(s, off, 64);

    __shared__ float wsum[4];
    if ((threadIdx.x & 63) == 0) wsum[threadIdx.x >> 6] = s;
    __syncthreads();
    if (threadIdx.x == 0) {
        const float inv_count = 1.0f / (float)(NB * CH * HH * WW);
        out[0] = ((wsum[0] + wsum[1]) + (wsum[2] + wsum[3])) * inv_count;
    }
}

extern "C" void kernel_launch(void* const* d_in, const int* in_sizes, int n_in,
                              void* d_out, int out_size, void* d_ws, size_t ws_size,
                              hipStream_t stream) {
    const float* image1  = (const float*)d_in[0];
    const float* image2  = (const float*)d_in[1];
    const float* filters = (const float*)d_in[2];
    float* out = (float*)d_out;
    float* block_sums = (float*)d_ws;   // 256 floats

    const int grid = NB * (HH / RPB);   // 256 blocks, one per (n, 4-row band)

    recon_charbonnier_kernel<<<grid, 256, 0, stream>>>(image1, image2, filters,
                                                       block_sums);
    final_reduce_kernel<<<1, 256, 0, stream>>>(block_sums, out);
}